// Round 4
// baseline (545.984 us; speedup 1.0000x reference)
//
#include <hip/hip_runtime.h>
#include <math.h>

// Problem constants (T=1024, B=4, E=1024, H=16, D=64)
#define TQ 1024
#define BBATCH 4
#define EDIM 1024
#define HHEADS 16
#define DHEAD 64

typedef __bf16 bf16x8 __attribute__((ext_vector_type(8)));
typedef __bf16 bf16x4 __attribute__((ext_vector_type(4)));
typedef float  f32x4  __attribute__((ext_vector_type(4)));

#define LDK 40  // GEMM LDS row stride (bf16): 32 + 8 pad

// ---------------------------------------------------------------------------
// MFMA GEMM: C = A * B^T + bias (fp32 in/out, bf16 MFMA internally).
// MODE 0: C[m][n] linear.  MODE 1: scatter to R[h][t][d].   (round-3 verified)
// ---------------------------------------------------------------------------
template<int MODE>
__global__ __launch_bounds__(256) void gemm_mfma_abt(
    const float* __restrict__ A, const float* __restrict__ B,
    const float* __restrict__ bias, float* __restrict__ C,
    int M, int N, int K)
{
    __shared__ __bf16 As[128 * LDK];
    __shared__ __bf16 Bs[128 * LDK];
    const int tid  = threadIdx.x;
    const int lane = tid & 63;
    const int wid  = tid >> 6;
    const int wr   = wid >> 1, wc = wid & 1;
    const int m0 = blockIdx.y * 128, n0 = blockIdx.x * 128;

    f32x4 acc[4][4] = {};

    const int sm0 = tid >> 2;
    const int sm1 = sm0 + 64;
    const int sk  = (tid & 3) << 3;

    const int fr = lane & 15;
    const int kg = (lane >> 4) << 3;

    for (int k0 = 0; k0 < K; k0 += 32) {
        float4 ra0a = *(const float4*)&A[(size_t)(m0 + sm0) * K + k0 + sk];
        float4 ra0b = *(const float4*)&A[(size_t)(m0 + sm0) * K + k0 + sk + 4];
        float4 ra1a = *(const float4*)&A[(size_t)(m0 + sm1) * K + k0 + sk];
        float4 ra1b = *(const float4*)&A[(size_t)(m0 + sm1) * K + k0 + sk + 4];
        float4 rb0a = *(const float4*)&B[(size_t)(n0 + sm0) * K + k0 + sk];
        float4 rb0b = *(const float4*)&B[(size_t)(n0 + sm0) * K + k0 + sk + 4];
        float4 rb1a = *(const float4*)&B[(size_t)(n0 + sm1) * K + k0 + sk];
        float4 rb1b = *(const float4*)&B[(size_t)(n0 + sm1) * K + k0 + sk + 4];

        __syncthreads();

        bf16x8 w;
        w[0]=(__bf16)ra0a.x; w[1]=(__bf16)ra0a.y; w[2]=(__bf16)ra0a.z; w[3]=(__bf16)ra0a.w;
        w[4]=(__bf16)ra0b.x; w[5]=(__bf16)ra0b.y; w[6]=(__bf16)ra0b.z; w[7]=(__bf16)ra0b.w;
        *(bf16x8*)&As[sm0 * LDK + sk] = w;
        w[0]=(__bf16)ra1a.x; w[1]=(__bf16)ra1a.y; w[2]=(__bf16)ra1a.z; w[3]=(__bf16)ra1a.w;
        w[4]=(__bf16)ra1b.x; w[5]=(__bf16)ra1b.y; w[6]=(__bf16)ra1b.z; w[7]=(__bf16)ra1b.w;
        *(bf16x8*)&As[sm1 * LDK + sk] = w;
        w[0]=(__bf16)rb0a.x; w[1]=(__bf16)rb0a.y; w[2]=(__bf16)rb0a.z; w[3]=(__bf16)rb0a.w;
        w[4]=(__bf16)rb0b.x; w[5]=(__bf16)rb0b.y; w[6]=(__bf16)rb0b.z; w[7]=(__bf16)rb0b.w;
        *(bf16x8*)&Bs[sm0 * LDK + sk] = w;
        w[0]=(__bf16)rb1a.x; w[1]=(__bf16)rb1a.y; w[2]=(__bf16)rb1a.z; w[3]=(__bf16)rb1a.w;
        w[4]=(__bf16)rb1b.x; w[5]=(__bf16)rb1b.y; w[6]=(__bf16)rb1b.z; w[7]=(__bf16)rb1b.w;
        *(bf16x8*)&Bs[sm1 * LDK + sk] = w;

        __syncthreads();

        bf16x8 af[4], bfr[4];
        #pragma unroll
        for (int i = 0; i < 4; ++i) {
            af[i]  = *(const bf16x8*)&As[(wr * 64 + i * 16 + fr) * LDK + kg];
            bfr[i] = *(const bf16x8*)&Bs[(wc * 64 + i * 16 + fr) * LDK + kg];
        }
        #pragma unroll
        for (int mi = 0; mi < 4; ++mi)
        #pragma unroll
        for (int ni = 0; ni < 4; ++ni)
            acc[mi][ni] = __builtin_amdgcn_mfma_f32_16x16x32_bf16(
                af[mi], bfr[ni], acc[mi][ni], 0, 0, 0);
    }

    const int fq = lane >> 4;
    #pragma unroll
    for (int mi = 0; mi < 4; ++mi)
    #pragma unroll
    for (int ni = 0; ni < 4; ++ni) {
        int row = m0 + wr * 64 + mi * 16 + fq * 4;
        int col = n0 + wc * 64 + ni * 16 + fr;
        float bv = bias[col];
        #pragma unroll
        for (int j = 0; j < 4; ++j) {
            float v = acc[mi][ni][j] + bv;
            if (MODE == 0) {
                C[(size_t)(row + j) * N + col] = v;
            } else {
                C[(((size_t)(col >> 6) << 10) + (row + j)) * 64 + (col & 63)] = v;
            }
        }
    }
}

// ---------------------------------------------------------------------------
// bias_dots: cK[bh][k] = rwb[h] . K[k,b,h,:]    cR[h][j] = rrb[h] . R[h][j][:]
// ---------------------------------------------------------------------------
__global__ __launch_bounds__(256) void bias_dots_kernel(
    const float* __restrict__ qkv, const float* __restrict__ Rm,
    const float* __restrict__ rwb, const float* __restrict__ rrb,
    float* __restrict__ cK, float* __restrict__ cR)
{
    int id = blockIdx.x * 256 + threadIdx.x;
    if (id < 65536) {
        int bh = id >> 10, k = id & 1023;
        int b = bh >> 4, h = bh & 15;
        const float* p = &qkv[((size_t)k * 4 + b) * 3072 + h * 192 + 64];
        const float* w = &rwb[h << 6];
        float s = 0.f;
        #pragma unroll
        for (int d = 0; d < 64; d += 4) {
            float4 v = *(const float4*)&p[d];
            s += v.x * w[d] + v.y * w[d + 1] + v.z * w[d + 2] + v.w * w[d + 3];
        }
        cK[id] = s;
    } else if (id < 81920) {
        int id2 = id - 65536;
        int h = id2 >> 10, j = id2 & 1023;
        const float* p = &Rm[(((size_t)h << 10) + j) * 64];
        const float* w = &rrb[h << 6];
        float s = 0.f;
        #pragma unroll
        for (int d = 0; d < 64; d += 4) {
            float4 v = *(const float4*)&p[d];
            s += v.x * w[d] + v.y * w[d + 1] + v.z * w[d + 2] + v.w * w[d + 3];
        }
        cR[id2] = s;
    }
}

// ---------------------------------------------------------------------------
// Fused score + softmax + PV kernel. One block = (bh, 64-row q-panel).
// Pass1: per K-tile MFMA scores (AC + shifted BD), raw -> attn, online m/sum.
// Pass2: re-read raw (L2), p=exp(s-m)/sum -> attn (f32), p,V^T -> LDS bf16,
//        PV MFMA accumulate. Then zero-fill kt>qt tiles, write ctx.
// LDS time-shared: pass1 {Qs,BDs,Ks,Rc0,Rc1}  pass2 {Pl,Vt}.
// ---------------------------------------------------------------------------
#define FLD 66  // bf16 LDS row stride (132B = 33 dwords -> ~2-way banks, free)

__global__ __launch_bounds__(256) void fused_attn_kernel(
    const float* __restrict__ qkv, const float* __restrict__ Rm,
    const float* __restrict__ cK, const float* __restrict__ cR,
    float* __restrict__ attn, float* __restrict__ ctx)
{
    const int qt = 15 - blockIdx.x;     // heavy panels first
    const int bh = blockIdx.y;
    const int b = bh >> 4, h = bh & 15;
    const int q0 = qt << 6;
    const int tid = threadIdx.x, lane = tid & 63, wid = tid >> 6;
    const int fr = lane & 15, fq = lane >> 4, kg = fq << 3;
    const int w16 = wid << 4;
    const int base0 = 960 - q0;

    __shared__ __align__(16) char smem[42752];
    __bf16* Qs  = (__bf16*)smem;                 // [64*FLD] pass1 prologue only
    __bf16* Pl  = (__bf16*)smem;                 // pass2 P tile (overlays Qs)
    float (*BDs)[68] = (float(*)[68])smem;       // pass1 spill, spans [0,17408)
    __bf16* Vt  = (__bf16*)(smem + 8448);        // pass2 V^T (overlays BDs tail)
    __bf16* Ks  = (__bf16*)(smem + 17408);
    __bf16* Rc0 = (__bf16*)(smem + 25856);
    __bf16* Rc1 = (__bf16*)(smem + 34304);

    // ---- prologue: stage Q tile + R chunk 0 (window rows base0..base0+63) ----
    #pragma unroll
    for (int s = 0; s < 4; ++s) {
        int idx = (s << 8) + tid, r = idx >> 4, dc = (idx & 15) << 2;
        float4 vq = *(const float4*)&qkv[((size_t)(q0 + r) * 4 + b) * 3072 + h * 192 + dc];
        float4 vr = *(const float4*)&Rm[(((size_t)h << 10) + base0 + r) * 64 + dc];
        bf16x4 w;
        w[0]=(__bf16)vq.x; w[1]=(__bf16)vq.y; w[2]=(__bf16)vq.z; w[3]=(__bf16)vq.w;
        *(bf16x4*)&Qs[r * FLD + dc] = w;
        w[0]=(__bf16)vr.x; w[1]=(__bf16)vr.y; w[2]=(__bf16)vr.z; w[3]=(__bf16)vr.w;
        *(bf16x4*)&Rc0[r * FLD + dc] = w;
    }
    __syncthreads();
    bf16x8 af0 = *(const bf16x8*)&Qs[(w16 + fr) * FLD + kg];
    bf16x8 af1 = *(const bf16x8*)&Qs[(w16 + fr) * FLD + 32 + kg];

    float mrow[4] = {-1e30f, -1e30f, -1e30f, -1e30f};
    float srow[4] = {0.f, 0.f, 0.f, 0.f};
    const f32x4 z4 = {0.f, 0.f, 0.f, 0.f};

    // ================= pass 1: scores + raw store + online stats =============
    for (int kt = 0; kt <= qt; ++kt) {
        const int k0 = kt << 6;
        __bf16* Rh0 = (kt & 1) ? Rc1 : Rc0;       // window half0 (invariant)
        __bf16* Rh1 = (kt & 1) ? Rc0 : Rc1;       // half1, staged this tile

        float4 kreg[4], rreg[4];
        #pragma unroll
        for (int s = 0; s < 4; ++s) {
            int idx = (s << 8) + tid, r = idx >> 4, dc = (idx & 15) << 2;
            kreg[s] = *(const float4*)&qkv[((size_t)(k0 + r) * 4 + b) * 3072 + h * 192 + 64 + dc];
            int j = base0 + k0 + 64 + r; if (j > 1023) j = 1023;
            rreg[s] = *(const float4*)&Rm[(((size_t)h << 10) + j) * 64 + dc];
        }
        __syncthreads();   // prev tile LDS reads done
        #pragma unroll
        for (int s = 0; s < 4; ++s) {
            int idx = (s << 8) + tid, r = idx >> 4, dc = (idx & 15) << 2;
            bf16x4 w;
            w[0]=(__bf16)kreg[s].x; w[1]=(__bf16)kreg[s].y; w[2]=(__bf16)kreg[s].z; w[3]=(__bf16)kreg[s].w;
            *(bf16x4*)&Ks[r * FLD + dc] = w;
            w[0]=(__bf16)rreg[s].x; w[1]=(__bf16)rreg[s].y; w[2]=(__bf16)rreg[s].z; w[3]=(__bf16)rreg[s].w;
            *(bf16x4*)&Rh1[r * FLD + dc] = w;
        }
        __syncthreads();   // tiles visible

        // AC = Q.K^T
        f32x4 aac[4];
        #pragma unroll
        for (int ni = 0; ni < 4; ++ni) {
            bf16x8 b0 = *(const bf16x8*)&Ks[(ni * 16 + fr) * FLD + kg];
            bf16x8 b1 = *(const bf16x8*)&Ks[(ni * 16 + fr) * FLD + 32 + kg];
            aac[ni] = __builtin_amdgcn_mfma_f32_16x16x32_bf16(af0, b0, z4, 0, 0, 0);
            aac[ni] = __builtin_amdgcn_mfma_f32_16x16x32_bf16(af1, b1, aac[ni], 0, 0, 0);
        }
        // BD half0 -> spill -> gather (widx<64)   [round-3 verified pattern]
        f32x4 abd[4];
        #pragma unroll
        for (int ni = 0; ni < 4; ++ni) {
            bf16x8 b0 = *(const bf16x8*)&Rh0[(ni * 16 + fr) * FLD + kg];
            bf16x8 b1 = *(const bf16x8*)&Rh0[(ni * 16 + fr) * FLD + 32 + kg];
            abd[ni] = __builtin_amdgcn_mfma_f32_16x16x32_bf16(af0, b0, z4, 0, 0, 0);
            abd[ni] = __builtin_amdgcn_mfma_f32_16x16x32_bf16(af1, b1, abd[ni], 0, 0, 0);
        }
        #pragma unroll
        for (int ni = 0; ni < 4; ++ni)
        #pragma unroll
        for (int j = 0; j < 4; ++j)
            BDs[w16 + fq * 4 + j][ni * 16 + fr] = abd[ni][j];
        asm volatile("s_waitcnt lgkmcnt(0)" ::: "memory");
        #pragma unroll
        for (int ni = 0; ni < 4; ++ni)
        #pragma unroll
        for (int j = 0; j < 4; ++j) {
            int lrow = w16 + fq * 4 + j;
            int widx = (ni * 16 + fr) - lrow + 63;
            if (widx < 64) aac[ni][j] += BDs[lrow][widx];
        }
        // BD half1 -> spill -> gather (widx>=64)
        #pragma unroll
        for (int ni = 0; ni < 4; ++ni) {
            bf16x8 b0 = *(const bf16x8*)&Rh1[(ni * 16 + fr) * FLD + kg];
            bf16x8 b1 = *(const bf16x8*)&Rh1[(ni * 16 + fr) * FLD + 32 + kg];
            abd[ni] = __builtin_amdgcn_mfma_f32_16x16x32_bf16(af0, b0, z4, 0, 0, 0);
            abd[ni] = __builtin_amdgcn_mfma_f32_16x16x32_bf16(af1, b1, abd[ni], 0, 0, 0);
        }
        #pragma unroll
        for (int ni = 0; ni < 4; ++ni)
        #pragma unroll
        for (int j = 0; j < 4; ++j)
            BDs[w16 + fq * 4 + j][ni * 16 + fr] = abd[ni][j];
        asm volatile("s_waitcnt lgkmcnt(0)" ::: "memory");
        #pragma unroll
        for (int ni = 0; ni < 4; ++ni)
        #pragma unroll
        for (int j = 0; j < 4; ++j) {
            int lrow = w16 + fq * 4 + j;
            int widx = (ni * 16 + fr) - lrow + 63;
            if (widx >= 64) aac[ni][j] += BDs[lrow][widx - 64];
        }

        // epilogue: +cK +cR, scale, mask(diag), raw store, online stats
        float sc[4][4];
        #pragma unroll
        for (int ni = 0; ni < 4; ++ni) {
            int lcol = ni * 16 + fr, k = k0 + lcol;
            float ckv = cK[(bh << 10) + k];
            #pragma unroll
            for (int j = 0; j < 4; ++j) {
                int lrow = w16 + fq * 4 + j;
                int widx = lcol - lrow + 63;
                int jidx = base0 + k0 + widx; if (jidx > 1023) jidx = 1023;
                float v = 0.125f * (aac[ni][j] + ckv + cR[(h << 10) + jidx]);
                if (kt == qt && lcol > lrow) v = -1e30f;   // causal mask
                sc[ni][j] = v;
                attn[((size_t)bh << 20) + ((size_t)(q0 + lrow) << 10) + k] = v;
            }
        }
        #pragma unroll
        for (int j = 0; j < 4; ++j) {
            float tmax = fmaxf(fmaxf(sc[0][j], sc[1][j]), fmaxf(sc[2][j], sc[3][j]));
            tmax = fmaxf(tmax, __shfl_xor(tmax, 1));
            tmax = fmaxf(tmax, __shfl_xor(tmax, 2));
            tmax = fmaxf(tmax, __shfl_xor(tmax, 4));
            tmax = fmaxf(tmax, __shfl_xor(tmax, 8));
            float mnew = fmaxf(mrow[j], tmax);
            float ps = __expf(sc[0][j] - mnew) + __expf(sc[1][j] - mnew)
                     + __expf(sc[2][j] - mnew) + __expf(sc[3][j] - mnew);
            ps += __shfl_xor(ps, 1); ps += __shfl_xor(ps, 2);
            ps += __shfl_xor(ps, 4); ps += __shfl_xor(ps, 8);
            srow[j] = srow[j] * __expf(mrow[j] - mnew) + ps;
            mrow[j] = mnew;
        }
    }

    float inv[4];
    #pragma unroll
    for (int j = 0; j < 4; ++j) inv[j] = 1.0f / srow[j];

    asm volatile("s_waitcnt vmcnt(0)" ::: "memory");  // raw stores visible
    __syncthreads();                                   // switch LDS usage

    // ================= pass 2: normalize + attn store + PV MFMA ==============
    f32x4 apv[4] = {};
    for (int kt = 0; kt <= qt; ++kt) {
        const int k0 = kt << 6;
        float4 vreg[4];
        #pragma unroll
        for (int s = 0; s < 4; ++s) {
            int idx = (s << 8) + tid, r = idx >> 4, dc = (idx & 15) << 2;
            vreg[s] = *(const float4*)&qkv[((size_t)(k0 + r) * 4 + b) * 3072 + h * 192 + 128 + dc];
        }
        float praw[4][4];
        #pragma unroll
        for (int ni = 0; ni < 4; ++ni)
        #pragma unroll
        for (int j = 0; j < 4; ++j)
            praw[ni][j] = attn[((size_t)bh << 20) +
                               ((size_t)(q0 + w16 + fq * 4 + j) << 10) + k0 + ni * 16 + fr];
        __syncthreads();   // prev tile Pl/Vt reads done
        // V^T -> LDS (transpose on store)
        #pragma unroll
        for (int s = 0; s < 4; ++s) {
            int idx = (s << 8) + tid, r = idx >> 4, dc = (idx & 15) << 2;
            Vt[(dc + 0) * FLD + r] = (__bf16)vreg[s].x;
            Vt[(dc + 1) * FLD + r] = (__bf16)vreg[s].y;
            Vt[(dc + 2) * FLD + r] = (__bf16)vreg[s].z;
            Vt[(dc + 3) * FLD + r] = (__bf16)vreg[s].w;
        }
        // p = exp(s-m)*inv  (masked raw=-1e30 -> exact 0); final attn + P tile
        #pragma unroll
        for (int ni = 0; ni < 4; ++ni)
        #pragma unroll
        for (int j = 0; j < 4; ++j) {
            float p = __expf(praw[ni][j] - mrow[j]) * inv[j];
            attn[((size_t)bh << 20) +
                 ((size_t)(q0 + w16 + fq * 4 + j) << 10) + k0 + ni * 16 + fr] = p;
            Pl[(w16 + fq * 4 + j) * FLD + ni * 16 + fr] = (__bf16)p;
        }
        __syncthreads();   // Pl/Vt visible
        // PV: ctx_panel += P * V
        bf16x8 pa0 = *(const bf16x8*)&Pl[(w16 + fr) * FLD + kg];
        bf16x8 pa1 = *(const bf16x8*)&Pl[(w16 + fr) * FLD + 32 + kg];
        #pragma unroll
        for (int ni = 0; ni < 4; ++ni) {
            bf16x8 bv0 = *(const bf16x8*)&Vt[(ni * 16 + fr) * FLD + kg];
            bf16x8 bv1 = *(const bf16x8*)&Vt[(ni * 16 + fr) * FLD + 32 + kg];
            apv[ni] = __builtin_amdgcn_mfma_f32_16x16x32_bf16(pa0, bv0, apv[ni], 0, 0, 0);
            apv[ni] = __builtin_amdgcn_mfma_f32_16x16x32_bf16(pa1, bv1, apv[ni], 0, 0, 0);
        }
    }

    // zero-fill upper-triangle tiles of this panel (mandatory attn output)
    for (int kt = qt + 1; kt < 16; ++kt) {
        const int k0 = kt << 6;
        #pragma unroll
        for (int s = 0; s < 4; ++s) {
            int idx = (s << 8) + tid, r = idx >> 4, c4 = (idx & 15) << 2;
            float4 z = {0.f, 0.f, 0.f, 0.f};
            *(float4*)&attn[((size_t)bh << 20) + ((size_t)(q0 + r) << 10) + k0 + c4] = z;
        }
    }
    // ctx panel store
    #pragma unroll
    for (int ni = 0; ni < 4; ++ni)
    #pragma unroll
    for (int j = 0; j < 4; ++j)
        ctx[((size_t)(q0 + w16 + fq * 4 + j) * 4 + b) * 1024 + (h << 6) + ni * 16 + fr]
            = apv[ni][j];
}

// ---------------------------------------------------------------------------
extern "C" void kernel_launch(void* const* d_in, const int* in_sizes, int n_in,
                              void* d_out, int out_size, void* d_ws, size_t ws_size,
                              hipStream_t stream)
{
    (void)in_sizes; (void)n_in; (void)out_size; (void)ws_size;
    const float* x     = (const float*)d_in[0];
    const float* pos   = (const float*)d_in[1];
    const float* w_in  = (const float*)d_in[2];
    const float* b_in  = (const float*)d_in[3];
    const float* w_out = (const float*)d_in[4];
    const float* b_out = (const float*)d_in[5];
    const float* w_pos = (const float*)d_in[6];
    const float* b_pos = (const float*)d_in[7];
    const float* rwb   = (const float*)d_in[8];
    const float* rrb   = (const float*)d_in[9];
    // d_in[10] = attn_mask: causal triu(k=1) by construction — handled analytically.

    float* out  = (float*)d_out;                       // (T,B,E)    4,194,304
    float* attn = out + (size_t)TQ * BBATCH * EDIM;    // (B,H,T,T) 67,108,864

    float* ws  = (float*)d_ws;
    float* qkv = ws;                                   // 4096 x 3072
    float* R   = qkv + (size_t)4096 * 3072;            // [H][T][D]
    float* ctx = R + (size_t)HHEADS * TQ * DHEAD;      // (T,B,E)
    // cK/cR live in the out region of d_out: consumed by fused_attn, then
    // overwritten by the final out-projection GEMM (stream-ordered, no race).
    float* cK  = out;                                  // [64][1024]
    float* cR  = out + 65536;                          // [16][1024]

    dim3 blk(256, 1, 1);

    // 1) qkv = x2d @ W_in^T + b_in        (bf16 MFMA, fp32 out)
    gemm_mfma_abt<0><<<dim3(3072 / 128, 4096 / 128), blk, 0, stream>>>(
        x, w_in, b_in, qkv, 4096, 3072, 1024);
    // 2) r_head_k = pos @ W_pos^T + b_pos -> R[h][t][d]
    gemm_mfma_abt<1><<<dim3(1024 / 128, 1024 / 128), blk, 0, stream>>>(
        pos, w_pos, b_pos, R, 1024, 1024, 1024);
    // 3) bias-dot corrections (exact fp32 split of (Q+bias).K / (Q+bias).R)
    bias_dots_kernel<<<dim3(320), blk, 0, stream>>>(qkv, R, rwb, rrb, cK, cR);
    // 4) fused scores + softmax + PV  (writes attn AND ctx)
    fused_attn_kernel<<<dim3(16, 64), blk, 0, stream>>>(qkv, R, cK, cR, attn, ctx);
    // 5) out = ctx2d @ W_out^T + b_out
    gemm_mfma_abt<0><<<dim3(1024 / 128, 4096 / 128), blk, 0, stream>>>(
        ctx, w_out, b_out, out, 4096, 1024, 1024);
}

// Round 5
// 371.848 us; speedup vs baseline: 1.4683x; 1.4683x over previous
//
#include <hip/hip_runtime.h>
#include <math.h>

// Problem constants (T=1024, B=4, E=1024, H=16, D=64)
#define TQ 1024
#define BBATCH 4
#define EDIM 1024
#define HHEADS 16
#define DHEAD 64

typedef __bf16 bf16x8 __attribute__((ext_vector_type(8)));
typedef __bf16 bf16x4 __attribute__((ext_vector_type(4)));
typedef float  f32x4  __attribute__((ext_vector_type(4)));

#define LDK 40  // GEMM LDS row stride (bf16): 32 + 8 pad

// ---------------------------------------------------------------------------
// MFMA GEMM: C = A * B^T + bias (fp32 in/out, bf16 MFMA internally).
// MODE 0: C[m][n] linear.  MODE 1: scatter to R[h][t][d].   (verified r2-r4)
// ---------------------------------------------------------------------------
template<int MODE>
__global__ __launch_bounds__(256) void gemm_mfma_abt(
    const float* __restrict__ A, const float* __restrict__ B,
    const float* __restrict__ bias, float* __restrict__ C,
    int M, int N, int K)
{
    __shared__ __bf16 As[128 * LDK];
    __shared__ __bf16 Bs[128 * LDK];
    const int tid  = threadIdx.x;
    const int lane = tid & 63;
    const int wid  = tid >> 6;
    const int wr   = wid >> 1, wc = wid & 1;
    const int m0 = blockIdx.y * 128, n0 = blockIdx.x * 128;

    f32x4 acc[4][4] = {};

    const int sm0 = tid >> 2;
    const int sm1 = sm0 + 64;
    const int sk  = (tid & 3) << 3;

    const int fr = lane & 15;
    const int kg = (lane >> 4) << 3;

    for (int k0 = 0; k0 < K; k0 += 32) {
        float4 ra0a = *(const float4*)&A[(size_t)(m0 + sm0) * K + k0 + sk];
        float4 ra0b = *(const float4*)&A[(size_t)(m0 + sm0) * K + k0 + sk + 4];
        float4 ra1a = *(const float4*)&A[(size_t)(m0 + sm1) * K + k0 + sk];
        float4 ra1b = *(const float4*)&A[(size_t)(m0 + sm1) * K + k0 + sk + 4];
        float4 rb0a = *(const float4*)&B[(size_t)(n0 + sm0) * K + k0 + sk];
        float4 rb0b = *(const float4*)&B[(size_t)(n0 + sm0) * K + k0 + sk + 4];
        float4 rb1a = *(const float4*)&B[(size_t)(n0 + sm1) * K + k0 + sk];
        float4 rb1b = *(const float4*)&B[(size_t)(n0 + sm1) * K + k0 + sk + 4];

        __syncthreads();

        bf16x8 w;
        w[0]=(__bf16)ra0a.x; w[1]=(__bf16)ra0a.y; w[2]=(__bf16)ra0a.z; w[3]=(__bf16)ra0a.w;
        w[4]=(__bf16)ra0b.x; w[5]=(__bf16)ra0b.y; w[6]=(__bf16)ra0b.z; w[7]=(__bf16)ra0b.w;
        *(bf16x8*)&As[sm0 * LDK + sk] = w;
        w[0]=(__bf16)ra1a.x; w[1]=(__bf16)ra1a.y; w[2]=(__bf16)ra1a.z; w[3]=(__bf16)ra1a.w;
        w[4]=(__bf16)ra1b.x; w[5]=(__bf16)ra1b.y; w[6]=(__bf16)ra1b.z; w[7]=(__bf16)ra1b.w;
        *(bf16x8*)&As[sm1 * LDK + sk] = w;
        w[0]=(__bf16)rb0a.x; w[1]=(__bf16)rb0a.y; w[2]=(__bf16)rb0a.z; w[3]=(__bf16)rb0a.w;
        w[4]=(__bf16)rb0b.x; w[5]=(__bf16)rb0b.y; w[6]=(__bf16)rb0b.z; w[7]=(__bf16)rb0b.w;
        *(bf16x8*)&Bs[sm0 * LDK + sk] = w;
        w[0]=(__bf16)rb1a.x; w[1]=(__bf16)rb1a.y; w[2]=(__bf16)rb1a.z; w[3]=(__bf16)rb1a.w;
        w[4]=(__bf16)rb1b.x; w[5]=(__bf16)rb1b.y; w[6]=(__bf16)rb1b.z; w[7]=(__bf16)rb1b.w;
        *(bf16x8*)&Bs[sm1 * LDK + sk] = w;

        __syncthreads();

        bf16x8 af[4], bfr[4];
        #pragma unroll
        for (int i = 0; i < 4; ++i) {
            af[i]  = *(const bf16x8*)&As[(wr * 64 + i * 16 + fr) * LDK + kg];
            bfr[i] = *(const bf16x8*)&Bs[(wc * 64 + i * 16 + fr) * LDK + kg];
        }
        #pragma unroll
        for (int mi = 0; mi < 4; ++mi)
        #pragma unroll
        for (int ni = 0; ni < 4; ++ni)
            acc[mi][ni] = __builtin_amdgcn_mfma_f32_16x16x32_bf16(
                af[mi], bfr[ni], acc[mi][ni], 0, 0, 0);
    }

    const int fq = lane >> 4;
    #pragma unroll
    for (int mi = 0; mi < 4; ++mi)
    #pragma unroll
    for (int ni = 0; ni < 4; ++ni) {
        int row = m0 + wr * 64 + mi * 16 + fq * 4;
        int col = n0 + wc * 64 + ni * 16 + fr;
        float bv = bias[col];
        #pragma unroll
        for (int j = 0; j < 4; ++j) {
            float v = acc[mi][ni][j] + bv;
            if (MODE == 0) {
                C[(size_t)(row + j) * N + col] = v;
            } else {
                C[(((size_t)(col >> 6) << 10) + (row + j)) * 64 + (col & 63)] = v;
            }
        }
    }
}

// ---------------------------------------------------------------------------
// bias_dots: cK[bh][k] = rwb[h] . K[k,b,h,:]    cR[h][j] = rrb[h] . R[h][j][:]
// ---------------------------------------------------------------------------
__global__ __launch_bounds__(256) void bias_dots_kernel(
    const float* __restrict__ qkv, const float* __restrict__ Rm,
    const float* __restrict__ rwb, const float* __restrict__ rrb,
    float* __restrict__ cK, float* __restrict__ cR)
{
    int id = blockIdx.x * 256 + threadIdx.x;
    if (id < 65536) {
        int bh = id >> 10, k = id & 1023;
        int b = bh >> 4, h = bh & 15;
        const float* p = &qkv[((size_t)k * 4 + b) * 3072 + h * 192 + 64];
        const float* w = &rwb[h << 6];
        float s = 0.f;
        #pragma unroll
        for (int d = 0; d < 64; d += 4) {
            float4 v = *(const float4*)&p[d];
            s += v.x * w[d] + v.y * w[d + 1] + v.z * w[d + 2] + v.w * w[d + 3];
        }
        cK[id] = s;
    } else if (id < 81920) {
        int id2 = id - 65536;
        int h = id2 >> 10, j = id2 & 1023;
        const float* p = &Rm[(((size_t)h << 10) + j) * 64];
        const float* w = &rrb[h << 6];
        float s = 0.f;
        #pragma unroll
        for (int d = 0; d < 64; d += 4) {
            float4 v = *(const float4*)&p[d];
            s += v.x * w[d] + v.y * w[d + 1] + v.z * w[d + 2] + v.w * w[d + 3];
        }
        cR[id2] = s;
    }
}

// ---------------------------------------------------------------------------
// MFMA score kernel (round-3 verified + diagonal mask). One block = one
// (bh, lower-triangle 64x64 tile). Writes RAW scores (masked = -1e30).
// ---------------------------------------------------------------------------
#define SLD 72

__global__ __launch_bounds__(256) void score_mfma_kernel(
    const float* __restrict__ qkv, const float* __restrict__ Rm,
    const float* __restrict__ cK, const float* __restrict__ cR,
    float* __restrict__ attn)
{
    int t = blockIdx.x;
    int qt = (int)((sqrtf(8.f * t + 1.f) - 1.f) * 0.5f);
    while ((qt + 1) * (qt + 2) / 2 <= t) ++qt;
    while (qt * (qt + 1) / 2 > t) --qt;
    int kt = t - qt * (qt + 1) / 2;

    const int bh = blockIdx.y;
    const int b = bh >> 4, h = bh & 15;
    const int q0 = qt << 6, k0 = kt << 6;
    const int tid = threadIdx.x, lane = tid & 63, wid = tid >> 6;
    const int fr = lane & 15, fq = lane >> 4, kg = fq << 3;
    const int w16 = wid << 4;
    const int base_j = k0 - q0 + 960;

    __shared__ __bf16 Qs[64 * SLD];
    __shared__ __bf16 Ks[64 * SLD];
    __shared__ __bf16 Rs[64 * SLD];
    __shared__ float  BDs[64][68];

    float4 qreg[4], kreg[4], r0reg[4], r1reg[4];
    #pragma unroll
    for (int s = 0; s < 4; ++s) {
        int idx = (s << 8) + tid;
        int r = idx >> 4, dc = (idx & 15) << 2;
        qreg[s] = *(const float4*)&qkv[((size_t)(q0 + r) * 4 + b) * 3072 + h * 192 + dc];
        kreg[s] = *(const float4*)&qkv[((size_t)(k0 + r) * 4 + b) * 3072 + h * 192 + 64 + dc];
        int j0 = base_j + r;       if (j0 > 1023) j0 = 1023;
        int j1 = base_j + 64 + r;  if (j1 > 1023) j1 = 1023;
        r0reg[s] = *(const float4*)&Rm[(((size_t)h << 10) + j0) * 64 + dc];
        r1reg[s] = *(const float4*)&Rm[(((size_t)h << 10) + j1) * 64 + dc];
    }
    #pragma unroll
    for (int s = 0; s < 4; ++s) {
        int idx = (s << 8) + tid;
        int r = idx >> 4, dc = (idx & 15) << 2;
        bf16x4 w;
        w[0]=(__bf16)qreg[s].x; w[1]=(__bf16)qreg[s].y; w[2]=(__bf16)qreg[s].z; w[3]=(__bf16)qreg[s].w;
        *(bf16x4*)&Qs[r * SLD + dc] = w;
        w[0]=(__bf16)kreg[s].x; w[1]=(__bf16)kreg[s].y; w[2]=(__bf16)kreg[s].z; w[3]=(__bf16)kreg[s].w;
        *(bf16x4*)&Ks[r * SLD + dc] = w;
        w[0]=(__bf16)r0reg[s].x; w[1]=(__bf16)r0reg[s].y; w[2]=(__bf16)r0reg[s].z; w[3]=(__bf16)r0reg[s].w;
        *(bf16x4*)&Rs[r * SLD + dc] = w;
    }
    __syncthreads();

    bf16x8 af0 = *(const bf16x8*)&Qs[(w16 + fr) * SLD + kg];
    bf16x8 af1 = *(const bf16x8*)&Qs[(w16 + fr) * SLD + 32 + kg];

    f32x4 aac[4], abd[4];
    const f32x4 zero4 = {0.f, 0.f, 0.f, 0.f};

    #pragma unroll
    for (int ni = 0; ni < 4; ++ni) {
        bf16x8 b0 = *(const bf16x8*)&Ks[(ni * 16 + fr) * SLD + kg];
        bf16x8 b1 = *(const bf16x8*)&Ks[(ni * 16 + fr) * SLD + 32 + kg];
        aac[ni] = __builtin_amdgcn_mfma_f32_16x16x32_bf16(af0, b0, zero4, 0, 0, 0);
        aac[ni] = __builtin_amdgcn_mfma_f32_16x16x32_bf16(af1, b1, aac[ni], 0, 0, 0);
    }
    #pragma unroll
    for (int ni = 0; ni < 4; ++ni) {
        bf16x8 b0 = *(const bf16x8*)&Rs[(ni * 16 + fr) * SLD + kg];
        bf16x8 b1 = *(const bf16x8*)&Rs[(ni * 16 + fr) * SLD + 32 + kg];
        abd[ni] = __builtin_amdgcn_mfma_f32_16x16x32_bf16(af0, b0, zero4, 0, 0, 0);
        abd[ni] = __builtin_amdgcn_mfma_f32_16x16x32_bf16(af1, b1, abd[ni], 0, 0, 0);
    }
    #pragma unroll
    for (int ni = 0; ni < 4; ++ni)
    #pragma unroll
    for (int j = 0; j < 4; ++j)
        BDs[w16 + fq * 4 + j][ni * 16 + fr] = abd[ni][j];
    asm volatile("s_waitcnt lgkmcnt(0)" ::: "memory");
    #pragma unroll
    for (int ni = 0; ni < 4; ++ni)
    #pragma unroll
    for (int j = 0; j < 4; ++j) {
        int lrow = w16 + fq * 4 + j;
        int widx = (ni * 16 + fr) - lrow + 63;
        if (widx < 64) aac[ni][j] += BDs[lrow][widx];
    }
    __syncthreads();

    #pragma unroll
    for (int s = 0; s < 4; ++s) {
        int idx = (s << 8) + tid;
        int r = idx >> 4, dc = (idx & 15) << 2;
        bf16x4 w;
        w[0]=(__bf16)r1reg[s].x; w[1]=(__bf16)r1reg[s].y; w[2]=(__bf16)r1reg[s].z; w[3]=(__bf16)r1reg[s].w;
        *(bf16x4*)&Rs[r * SLD + dc] = w;
    }
    __syncthreads();

    #pragma unroll
    for (int ni = 0; ni < 4; ++ni) {
        bf16x8 b0 = *(const bf16x8*)&Rs[(ni * 16 + fr) * SLD + kg];
        bf16x8 b1 = *(const bf16x8*)&Rs[(ni * 16 + fr) * SLD + 32 + kg];
        abd[ni] = __builtin_amdgcn_mfma_f32_16x16x32_bf16(af0, b0, zero4, 0, 0, 0);
        abd[ni] = __builtin_amdgcn_mfma_f32_16x16x32_bf16(af1, b1, abd[ni], 0, 0, 0);
    }
    #pragma unroll
    for (int ni = 0; ni < 4; ++ni)
    #pragma unroll
    for (int j = 0; j < 4; ++j)
        BDs[w16 + fq * 4 + j][ni * 16 + fr] = abd[ni][j];
    asm volatile("s_waitcnt lgkmcnt(0)" ::: "memory");
    #pragma unroll
    for (int ni = 0; ni < 4; ++ni)
    #pragma unroll
    for (int j = 0; j < 4; ++j) {
        int lrow = w16 + fq * 4 + j;
        int widx = (ni * 16 + fr) - lrow + 63;
        if (widx >= 64) aac[ni][j] += BDs[lrow][widx - 64];
    }

    // epilogue: +cK +cR, scale, diagonal mask, RAW store
    #pragma unroll
    for (int ni = 0; ni < 4; ++ni) {
        int lcol = ni * 16 + fr;
        int k = k0 + lcol;
        float ckv = cK[(bh << 10) + k];
        #pragma unroll
        for (int j = 0; j < 4; ++j) {
            int lrow = w16 + fq * 4 + j;
            int q = q0 + lrow;
            int widx = lcol - lrow + 63;
            int jidx = base_j + widx; if (jidx > 1023) jidx = 1023;
            float crv = cR[(h << 10) + jidx];
            float v = 0.125f * (aac[ni][j] + ckv + crv);
            if (kt == qt && lcol > lrow) v = -1e30f;   // causal mask (raw)
            attn[((((size_t)bh << 10) + q) << 10) + k] = v;
        }
    }
}

// ---------------------------------------------------------------------------
// row_stats: one wave per (bh,q) row. Online max/sum over k<=q only.
// stats[row] = {m, 1/sum}.
// ---------------------------------------------------------------------------
__global__ __launch_bounds__(256) void row_stats_kernel(
    const float* __restrict__ attn, float2* __restrict__ stats)
{
    const int gw = blockIdx.x * 4 + (threadIdx.x >> 6);
    const int bh = gw >> 10, q = gw & 1023;
    const int lane = threadIdx.x & 63;
    const float* row = attn + ((size_t)bh << 20) + ((size_t)q << 10);

    float m = -1e30f, s = 0.f;
    const int nc = (q >> 8) + 1;   // 256-float chunks covering k<=q
    for (int c = 0; c < nc; ++c) {
        int base = (c << 8) + (lane << 2);
        float4 v = *(const float4*)&row[base];
        bool c0 = base + 0 <= q, c1 = base + 1 <= q, c2 = base + 2 <= q, c3 = base + 3 <= q;
        float e0 = c0 ? v.x : -1e30f, e1 = c1 ? v.y : -1e30f;
        float e2 = c2 ? v.z : -1e30f, e3 = c3 ? v.w : -1e30f;
        float tm = fmaxf(fmaxf(e0, e1), fmaxf(e2, e3));
        float mn = fmaxf(m, tm);
        s *= __expf(m - mn);                    // m==mn==-1e30 -> exp(0), s==0 ok
        if (c0) s += __expf(v.x - mn);
        if (c1) s += __expf(v.y - mn);
        if (c2) s += __expf(v.z - mn);
        if (c3) s += __expf(v.w - mn);
        m = mn;
    }
    #pragma unroll
    for (int off = 1; off < 64; off <<= 1) {
        float mo = __shfl_xor(m, off), so = __shfl_xor(s, off);
        float mn = fmaxf(m, mo);
        s = s * __expf(m - mn) + so * __expf(mo - mn);
        m = mn;
    }
    if (lane == 0) stats[gw] = make_float2(m, 1.0f / s);
}

// ---------------------------------------------------------------------------
// ctx_norm: block per (bh, 64-row q-panel). Reads raw scores in fragment
// layout, p = exp(raw-m)*inv -> final attn (f32) + bf16 P in LDS; V^T bf16
// in LDS; PV via MFMA. Zero-fills kt>qt tiles. Writes ctx.
// ---------------------------------------------------------------------------
#define FLD 66

__global__ __launch_bounds__(256) void ctx_norm_kernel(
    const float* __restrict__ qkv, const float2* __restrict__ stats,
    float* __restrict__ attn, float* __restrict__ ctx)
{
    const int qt = 15 - blockIdx.x;     // heavy panels first
    const int bh = blockIdx.y;
    const int b = bh >> 4, h = bh & 15;
    const int q0 = qt << 6;
    const int tid = threadIdx.x, lane = tid & 63, wid = tid >> 6;
    const int fr = lane & 15, fq = lane >> 4, kg = fq << 3;
    const int w16 = wid << 4;

    __shared__ __bf16 Pl[64 * FLD];
    __shared__ __bf16 Vt[64 * FLD];

    float mrow[4], inv[4];
    #pragma unroll
    for (int j = 0; j < 4; ++j) {
        float2 st = stats[(bh << 10) + q0 + w16 + fq * 4 + j];
        mrow[j] = st.x; inv[j] = st.y;
    }

    f32x4 apv[4] = {};
    for (int kt = 0; kt <= qt; ++kt) {
        const int k0 = kt << 6;
        float4 vreg[4];
        #pragma unroll
        for (int s = 0; s < 4; ++s) {
            int idx = (s << 8) + tid, r = idx >> 4, dc = (idx & 15) << 2;
            vreg[s] = *(const float4*)&qkv[((size_t)(k0 + r) * 4 + b) * 3072 + h * 192 + 128 + dc];
        }
        float praw[4][4];
        #pragma unroll
        for (int ni = 0; ni < 4; ++ni)
        #pragma unroll
        for (int j = 0; j < 4; ++j)
            praw[ni][j] = attn[((size_t)bh << 20) +
                               ((size_t)(q0 + w16 + fq * 4 + j) << 10) + k0 + ni * 16 + fr];
        __syncthreads();   // prev tile Pl/Vt reads done
        #pragma unroll
        for (int s = 0; s < 4; ++s) {
            int idx = (s << 8) + tid, r = idx >> 4, dc = (idx & 15) << 2;
            Vt[(dc + 0) * FLD + r] = (__bf16)vreg[s].x;
            Vt[(dc + 1) * FLD + r] = (__bf16)vreg[s].y;
            Vt[(dc + 2) * FLD + r] = (__bf16)vreg[s].z;
            Vt[(dc + 3) * FLD + r] = (__bf16)vreg[s].w;
        }
        #pragma unroll
        for (int ni = 0; ni < 4; ++ni)
        #pragma unroll
        for (int j = 0; j < 4; ++j) {
            float p = __expf(praw[ni][j] - mrow[j]) * inv[j];   // masked raw -> 0
            attn[((size_t)bh << 20) +
                 ((size_t)(q0 + w16 + fq * 4 + j) << 10) + k0 + ni * 16 + fr] = p;
            Pl[(w16 + fq * 4 + j) * FLD + ni * 16 + fr] = (__bf16)p;
        }
        __syncthreads();   // Pl/Vt visible
        bf16x8 pa0 = *(const bf16x8*)&Pl[(w16 + fr) * FLD + kg];
        bf16x8 pa1 = *(const bf16x8*)&Pl[(w16 + fr) * FLD + 32 + kg];
        #pragma unroll
        for (int ni = 0; ni < 4; ++ni) {
            bf16x8 bv0 = *(const bf16x8*)&Vt[(ni * 16 + fr) * FLD + kg];
            bf16x8 bv1 = *(const bf16x8*)&Vt[(ni * 16 + fr) * FLD + 32 + kg];
            apv[ni] = __builtin_amdgcn_mfma_f32_16x16x32_bf16(pa0, bv0, apv[ni], 0, 0, 0);
            apv[ni] = __builtin_amdgcn_mfma_f32_16x16x32_bf16(pa1, bv1, apv[ni], 0, 0, 0);
        }
    }

    // zero-fill upper-triangle tiles (mandatory attn output, coalesced)
    for (int kt = qt + 1; kt < 16; ++kt) {
        const int k0 = kt << 6;
        #pragma unroll
        for (int s = 0; s < 4; ++s) {
            int idx = (s << 8) + tid, r = idx >> 4, c4 = (idx & 15) << 2;
            float4 z = {0.f, 0.f, 0.f, 0.f};
            *(float4*)&attn[((size_t)bh << 20) + ((size_t)(q0 + r) << 10) + k0 + c4] = z;
        }
    }
    #pragma unroll
    for (int ni = 0; ni < 4; ++ni)
    #pragma unroll
    for (int j = 0; j < 4; ++j)
        ctx[((size_t)(q0 + w16 + fq * 4 + j) * 4 + b) * 1024 + (h << 6) + ni * 16 + fr]
            = apv[ni][j];
}

// ---------------------------------------------------------------------------
extern "C" void kernel_launch(void* const* d_in, const int* in_sizes, int n_in,
                              void* d_out, int out_size, void* d_ws, size_t ws_size,
                              hipStream_t stream)
{
    (void)in_sizes; (void)n_in; (void)out_size; (void)ws_size;
    const float* x     = (const float*)d_in[0];
    const float* pos   = (const float*)d_in[1];
    const float* w_in  = (const float*)d_in[2];
    const float* b_in  = (const float*)d_in[3];
    const float* w_out = (const float*)d_in[4];
    const float* b_out = (const float*)d_in[5];
    const float* w_pos = (const float*)d_in[6];
    const float* b_pos = (const float*)d_in[7];
    const float* rwb   = (const float*)d_in[8];
    const float* rrb   = (const float*)d_in[9];
    // d_in[10] = attn_mask: causal triu(k=1) by construction — handled analytically.

    float* out  = (float*)d_out;                       // (T,B,E)    4,194,304
    float* attn = out + (size_t)TQ * BBATCH * EDIM;    // (B,H,T,T) 67,108,864

    float* ws  = (float*)d_ws;
    float* qkv = ws;                                   // 4096 x 3072
    float* R   = qkv + (size_t)4096 * 3072;            // [H][T][D]
    float* ctx = R + (size_t)HHEADS * TQ * DHEAD;      // (T,B,E)
    // cK/cR/stats live in the out region of d_out: all consumed before the
    // final out-projection GEMM overwrites it (stream-ordered, no race).
    float*  cK    = out;                               // [64][1024]
    float*  cR    = out + 65536;                       // [16][1024]
    float2* stats = (float2*)(out + 81920);            // [65536] {m, 1/sum}

    dim3 blk(256, 1, 1);

    // 1) qkv = x2d @ W_in^T + b_in        (bf16 MFMA, fp32 out)
    gemm_mfma_abt<0><<<dim3(3072 / 128, 4096 / 128), blk, 0, stream>>>(
        x, w_in, b_in, qkv, 4096, 3072, 1024);
    // 2) r_head_k = pos @ W_pos^T + b_pos -> R[h][t][d]
    gemm_mfma_abt<1><<<dim3(1024 / 128, 1024 / 128), blk, 0, stream>>>(
        pos, w_pos, b_pos, R, 1024, 1024, 1024);
    // 3) bias-dot corrections (exact fp32 split of (Q+bias).K / (Q+bias).R)
    bias_dots_kernel<<<dim3(320), blk, 0, stream>>>(qkv, R, rwb, rrb, cK, cR);
    // 4) raw scores (masked -1e30 on diagonal) -> attn region, 8704-wide grid
    score_mfma_kernel<<<dim3(136, 64), blk, 0, stream>>>(qkv, R, cK, cR, attn);
    // 5) per-row max / inv-sum over k<=q
    row_stats_kernel<<<dim3(16384), blk, 0, stream>>>(attn, stats);
    // 6) normalize + final attn + PV MFMA + zero-fill; writes ctx
    ctx_norm_kernel<<<dim3(16, 64), blk, 0, stream>>>(qkv, stats, attn, ctx);
    // 7) out = ctx2d @ W_out^T + b_out
    gemm_mfma_abt<0><<<dim3(1024 / 128, 4096 / 128), blk, 0, stream>>>(
        ctx, w_out, b_out, out, 4096, 1024, 1024);
}